// Round 1
// baseline (441.581 us; speedup 1.0000x reference)
//
#include <hip/hip_runtime.h>
#include <hip/hip_bf16.h>

// Problem constants (from reference setup_inputs)
constexpr int B      = 16384;
constexpr int D_IN   = 1024;
constexpr int D_OUT  = 256;
constexpr int NCLS   = 1000;
constexpr int NCAT   = 512;   // concat of W1 (256 rows) and W2 (256 rows)

// ---------------- workspace layout (in floats / ints) ----------------
// floats:
//   Y2   : B*D_OUT           @ 0
//   t    : NCLS*D_OUT        @ Y2_end
//   Z    : NCLS*D_OUT        @ t_end
//   T2   : D_OUT             @ Z_end
// ints (after float region):
//   cnt[NCLS], offs[NCLS], cursor[NCLS], rowlist[B]
constexpr size_t OFF_Y2 = 0;
constexpr size_t OFF_T  = OFF_Y2 + (size_t)B * D_OUT;
constexpr size_t OFF_Z  = OFF_T  + (size_t)NCLS * D_OUT;
constexpr size_t OFF_T2 = OFF_Z  + (size_t)NCLS * D_OUT;
constexpr size_t OFF_INT = OFF_T2 + D_OUT;           // float index where int region starts

// ---------------- kernels ----------------

__global__ void zero_ints_kernel(int* p, int n) {
    int i = blockIdx.x * blockDim.x + threadIdx.x;
    if (i < n) p[i] = 0;
}

__global__ void hist_kernel(const int* __restrict__ label, int* __restrict__ cnt) {
    int i = blockIdx.x * blockDim.x + threadIdx.x;
    if (i < B) atomicAdd(&cnt[label[i]], 1);
}

// exclusive prefix over NCLS counts, 1 block of 1024 threads, ping-pong scan
__global__ void prefix_kernel(const int* __restrict__ cnt, int* __restrict__ offs) {
    __shared__ int bufA[1024];
    __shared__ int bufB[1024];
    int t = threadIdx.x;
    int v = (t < NCLS) ? cnt[t] : 0;
    bufA[t] = v;
    __syncthreads();
    int* src = bufA;
    int* dst = bufB;
    for (int off = 1; off < 1024; off <<= 1) {
        int s = src[t];
        if (t >= off) s += src[t - off];
        dst[t] = s;
        __syncthreads();
        int* tmp = src; src = dst; dst = tmp;
    }
    if (t < NCLS) offs[t] = src[t] - v;   // inclusive -> exclusive
}

__global__ void scatter_kernel(const int* __restrict__ label,
                               const int* __restrict__ offs,
                               int* __restrict__ cursor,
                               int* __restrict__ rowlist) {
    int i = blockIdx.x * blockDim.x + threadIdx.x;
    if (i < B) {
        int c = label[i];
        int p = atomicAdd(&cursor[c], 1);
        rowlist[offs[c] + p] = i;
    }
}

// Fused GEMM: P = x @ [W1;W2]^T.  Tile 64x64, BK=16, 256 threads, 4x4/thread.
// n < 256  -> d_out[m,n] = P + b1[n]
// n >= 256 -> Y2[m,n-256] = P
__global__ __launch_bounds__(256)
void gemm_kernel(const float* __restrict__ x,
                 const float* __restrict__ W1,
                 const float* __restrict__ b1,
                 const float* __restrict__ W2,
                 float* __restrict__ out,
                 float* __restrict__ Y2) {
    constexpr int BM = 64, BN = 64, BK = 16;
    __shared__ float As[BK][BM];
    __shared__ float Bs[BK][BN];

    const int tid = threadIdx.x;
    const int tx = tid & 15;        // 0..15 -> n
    const int ty = tid >> 4;        // 0..15 -> m
    const int bm = blockIdx.x * BM; // 0..16320
    const int bn = blockIdx.y * BN; // 0..448

    // loader mapping: each thread loads one float4 of A and one of B per BK step
    const int lm = tid >> 2;          // 0..63 (row within tile)
    const int lk = (tid & 3) << 2;    // 0,4,8,12 (k within BK chunk)

    const float* __restrict__ arow = x + (size_t)(bm + lm) * D_IN + lk;
    const int n_g = bn + lm;
    const float* __restrict__ brow =
        (n_g < D_OUT) ? (W1 + (size_t)n_g * D_IN + lk)
                      : (W2 + (size_t)(n_g - D_OUT) * D_IN + lk);

    float acc[4][4] = {};

    for (int k0 = 0; k0 < D_IN; k0 += BK) {
        float4 av = *(const float4*)(arow + k0);
        float4 bv = *(const float4*)(brow + k0);
        __syncthreads();   // previous iter's LDS reads done
        As[lk + 0][lm] = av.x; As[lk + 1][lm] = av.y;
        As[lk + 2][lm] = av.z; As[lk + 3][lm] = av.w;
        Bs[lk + 0][lm] = bv.x; Bs[lk + 1][lm] = bv.y;
        Bs[lk + 2][lm] = bv.z; Bs[lk + 3][lm] = bv.w;
        __syncthreads();
#pragma unroll
        for (int kk = 0; kk < BK; ++kk) {
            float4 a = *(const float4*)&As[kk][ty << 2];
            float4 b = *(const float4*)&Bs[kk][tx << 2];
            float am[4] = {a.x, a.y, a.z, a.w};
            float bn_[4] = {b.x, b.y, b.z, b.w};
#pragma unroll
            for (int i = 0; i < 4; ++i)
#pragma unroll
                for (int j = 0; j < 4; ++j)
                    acc[i][j] += am[i] * bn_[j];
        }
    }

    // epilogue: whole block is either the W1 half or the W2 half (bn multiple of 64)
    if (bn < D_OUT) {
        float4 b1v = *(const float4*)(b1 + bn + (tx << 2));
#pragma unroll
        for (int i = 0; i < 4; ++i) {
            int m = bm + (ty << 2) + i;
            float4 v = {acc[i][0] + b1v.x, acc[i][1] + b1v.y,
                        acc[i][2] + b1v.z, acc[i][3] + b1v.w};
            *(float4*)(out + (size_t)m * D_OUT + bn + (tx << 2)) = v;
        }
    } else {
        int nb = bn - D_OUT;
#pragma unroll
        for (int i = 0; i < 4; ++i) {
            int m = bm + (ty << 2) + i;
            float4 v = {acc[i][0], acc[i][1], acc[i][2], acc[i][3]};
            *(float4*)(Y2 + (size_t)m * D_OUT + nb + (tx << 2)) = v;
        }
    }
}

// per-class sum of Y2 rows: block c, thread j covers column j
__global__ void classsum_kernel(const float* __restrict__ Y2,
                                const int* __restrict__ offs,
                                const int* __restrict__ cnt,
                                const int* __restrict__ rowlist,
                                float* __restrict__ t_out) {
    int c = blockIdx.x;
    int j = threadIdx.x;
    int o = offs[c], n = cnt[c];
    float acc = 0.f;
    for (int r = 0; r < n; ++r) {
        int row = rowlist[o + r];
        acc += Y2[(size_t)row * D_OUT + j];
    }
    t_out[(size_t)c * D_OUT + j] = acc;
}

__global__ void total_kernel(const float* __restrict__ t_in, float* __restrict__ T2) {
    int j = threadIdx.x;
    float acc = 0.f;
    for (int c = 0; c < NCLS; ++c) acc += t_in[(size_t)c * D_OUT + j];
    T2[j] = acc;
}

__global__ void z_kernel(const float* __restrict__ t_in,
                         const float* __restrict__ T2,
                         const float* __restrict__ b2,
                         const int* __restrict__ cnt,
                         float* __restrict__ Z) {
    int c = blockIdx.x;
    int j = threadIdx.x;
    int d = B - cnt[c];
    float v = b2[j];
    if (d > 0) v += (T2[j] - t_in[(size_t)c * D_OUT + j]) / (float)d;
    Z[(size_t)c * D_OUT + j] = v;
}

// out[i,:] += Z[label[i],:]   (float4 granularity)
__global__ void final_kernel(float* __restrict__ out,
                             const float* __restrict__ Z,
                             const int* __restrict__ label) {
    int idx = blockIdx.x * blockDim.x + threadIdx.x;  // float4 index
    int i  = idx >> 6;            // 64 float4 per row (256 floats)
    int j4 = (idx & 63) << 2;
    int c = label[i];
    float4 o = *(float4*)(out + (size_t)idx * 4);
    float4 z = *(const float4*)(Z + (size_t)c * D_OUT + j4);
    o.x += z.x; o.y += z.y; o.z += z.z; o.w += z.w;
    *(float4*)(out + (size_t)idx * 4) = o;
}

// ---------------- launcher ----------------
extern "C" void kernel_launch(void* const* d_in, const int* in_sizes, int n_in,
                              void* d_out, int out_size, void* d_ws, size_t ws_size,
                              hipStream_t stream) {
    const float* x    = (const float*)d_in[0];
    const int*   lab  = (const int*)d_in[1];
    const float* W1_w = (const float*)d_in[2];
    const float* W1_b = (const float*)d_in[3];
    const float* W2_w = (const float*)d_in[4];
    const float* W2_b = (const float*)d_in[5];
    float* out = (float*)d_out;

    float* ws   = (float*)d_ws;
    float* Y2   = ws + OFF_Y2;
    float* t_c  = ws + OFF_T;
    float* Z    = ws + OFF_Z;
    float* T2   = ws + OFF_T2;
    int*   ints = (int*)(ws + OFF_INT);
    int* cnt     = ints;
    int* offs    = ints + NCLS;
    int* cursor  = ints + 2 * NCLS;
    int* rowlist = ints + 3 * NCLS;

    // 1. zero cnt/offs/cursor (ws is poisoned each launch)
    zero_ints_kernel<<<(3 * NCLS + 255) / 256, 256, 0, stream>>>(ints, 3 * NCLS);
    // 2. histogram
    hist_kernel<<<B / 256, 256, 0, stream>>>(lab, cnt);
    // 3. exclusive prefix
    prefix_kernel<<<1, 1024, 0, stream>>>(cnt, offs);
    // 4. scatter row indices
    scatter_kernel<<<B / 256, 256, 0, stream>>>(lab, offs, cursor, rowlist);
    // 5. fused GEMM: Y1(+b1) -> out, Y2 -> ws
    dim3 ggrid(B / 64, NCAT / 64);
    gemm_kernel<<<ggrid, 256, 0, stream>>>(x, W1_w, W1_b, W2_w, out, Y2);
    // 6. per-class sums of Y2
    classsum_kernel<<<NCLS, D_OUT, 0, stream>>>(Y2, offs, cnt, rowlist, t_c);
    // 7. total over classes
    total_kernel<<<1, D_OUT, 0, stream>>>(t_c, T2);
    // 8. Z table
    z_kernel<<<NCLS, D_OUT, 0, stream>>>(t_c, T2, W2_b, cnt, Z);
    // 9. gather-add
    final_kernel<<<(B * D_OUT / 4) / 256, 256, 0, stream>>>(out, Z, lab);
}

// Round 2
// 194.491 us; speedup vs baseline: 2.2704x; 2.2704x over previous
//
#include <hip/hip_runtime.h>
#include <hip/hip_bf16.h>

// Problem constants
constexpr int B      = 16384;
constexpr int D_IN   = 1024;
constexpr int D_OUT  = 256;
constexpr int NCLS   = 1000;
constexpr int NCAT   = 512;   // concat rows of W1 (256) and W2 (256)

// ---------------- workspace layout (byte offsets) ----------------
// xb  : B*D_IN bf16          = 33,554,432 B @ 0
// Wb  : NCAT*D_IN bf16       =  1,048,576 B
// Y2  : B*D_OUT f32          = 16,777,216 B
// t   : NCLS*D_OUT f32       =  1,024,000 B
// Z   : NCLS*D_OUT f32       =  1,024,000 B
// T2  : D_OUT f32            =      1,024 B
// ints: cnt[NCLS] offs[NCLS] cursor[NCLS] rowlist[B]
constexpr size_t OFF_XB  = 0;
constexpr size_t OFF_WB  = OFF_XB + (size_t)B * D_IN * 2;
constexpr size_t OFF_Y2  = OFF_WB + (size_t)NCAT * D_IN * 2;
constexpr size_t OFF_T   = OFF_Y2 + (size_t)B * D_OUT * 4;
constexpr size_t OFF_Z   = OFF_T  + (size_t)NCLS * D_OUT * 4;
constexpr size_t OFF_T2  = OFF_Z  + (size_t)NCLS * D_OUT * 4;
constexpr size_t OFF_INT = OFF_T2 + (size_t)D_OUT * 4;   // adjacent to T2 (zeroed together)

typedef short bf16x8 __attribute__((ext_vector_type(8)));
typedef float f32x4  __attribute__((ext_vector_type(4)));

// fp32 -> bf16 round-to-nearest-even (bit trick; NaN not present in this data)
__device__ __forceinline__ unsigned short f2bf(float f) {
    unsigned int u = __float_as_uint(f);
    return (unsigned short)((u + 0x7FFFu + ((u >> 16) & 1u)) >> 16);
}

// async global->LDS, 16B per lane; lds ptr must be wave-uniform base (+lane*16 implied)
__device__ __forceinline__ void async16(const unsigned short* g, unsigned short* l) {
    __builtin_amdgcn_global_load_lds(
        (const __attribute__((address_space(1))) void*)g,
        (__attribute__((address_space(3))) void*)l,
        16, 0, 0);
}

// ---------------- small kernels ----------------

__global__ void zero_ints_kernel(int* p, int n) {
    int i = blockIdx.x * blockDim.x + threadIdx.x;
    if (i < n) p[i] = 0;
}

__global__ void hist_kernel(const int* __restrict__ label, int* __restrict__ cnt) {
    int i = blockIdx.x * blockDim.x + threadIdx.x;
    if (i < B) atomicAdd(&cnt[label[i]], 1);
}

__global__ void prefix_kernel(const int* __restrict__ cnt, int* __restrict__ offs) {
    __shared__ int bufA[1024];
    __shared__ int bufB[1024];
    int t = threadIdx.x;
    int v = (t < NCLS) ? cnt[t] : 0;
    bufA[t] = v;
    __syncthreads();
    int* src = bufA;
    int* dst = bufB;
    for (int off = 1; off < 1024; off <<= 1) {
        int s = src[t];
        if (t >= off) s += src[t - off];
        dst[t] = s;
        __syncthreads();
        int* tmp = src; src = dst; dst = tmp;
    }
    if (t < NCLS) offs[t] = src[t] - v;
}

__global__ void scatter_kernel(const int* __restrict__ label,
                               const int* __restrict__ offs,
                               int* __restrict__ cursor,
                               int* __restrict__ rowlist) {
    int i = blockIdx.x * blockDim.x + threadIdx.x;
    if (i < B) {
        int c = label[i];
        int p = atomicAdd(&cursor[c], 1);
        rowlist[offs[c] + p] = i;
    }
}

// fp32 -> bf16 bulk convert (8 elements/thread)
__global__ void cvt_x_kernel(const float* __restrict__ src, unsigned short* __restrict__ dst) {
    int i = (blockIdx.x * blockDim.x + threadIdx.x) * 8;
    float4 a = *(const float4*)(src + i);
    float4 b = *(const float4*)(src + i + 4);
    union { unsigned short u[8]; ushort4 q[2]; } r;
    r.u[0] = f2bf(a.x); r.u[1] = f2bf(a.y); r.u[2] = f2bf(a.z); r.u[3] = f2bf(a.w);
    r.u[4] = f2bf(b.x); r.u[5] = f2bf(b.y); r.u[6] = f2bf(b.z); r.u[7] = f2bf(b.w);
    *(ushort4*)(dst + i)     = r.q[0];
    *(ushort4*)(dst + i + 4) = r.q[1];
}

// concat-convert W1,W2 -> Wb [512][1024] bf16
__global__ void cvt_w_kernel(const float* __restrict__ W1, const float* __restrict__ W2,
                             unsigned short* __restrict__ dst) {
    int i = (blockIdx.x * blockDim.x + threadIdx.x) * 8;  // [0, 512*1024)
    const float* src = (i < D_OUT * D_IN) ? (W1 + i) : (W2 + (i - D_OUT * D_IN));
    float4 a = *(const float4*)(src);
    float4 b = *(const float4*)(src + 4);
    union { unsigned short u[8]; ushort4 q[2]; } r;
    r.u[0] = f2bf(a.x); r.u[1] = f2bf(a.y); r.u[2] = f2bf(a.z); r.u[3] = f2bf(a.w);
    r.u[4] = f2bf(b.x); r.u[5] = f2bf(b.y); r.u[6] = f2bf(b.z); r.u[7] = f2bf(b.w);
    *(ushort4*)(dst + i)     = r.q[0];
    *(ushort4*)(dst + i + 4) = r.q[1];
}

// ---------------- MFMA GEMM: P = xb @ Wb^T ----------------
// 128x128 tile, BK=32, 256 threads (4 waves 2x2, each 64x64 via 4x4 of 16x16x32).
// bn < 256  -> out[m][n] = P + b1[n]
// bn >= 256 -> Y2[m][n-256] = P
__global__ __launch_bounds__(256)
void gemm_mfma_kernel(const unsigned short* __restrict__ A,   // [B][1024] bf16
                      const unsigned short* __restrict__ W,   // [512][1024] bf16
                      const float* __restrict__ b1,
                      float* __restrict__ out,
                      float* __restrict__ Y2) {
    __shared__ unsigned short As[128 * 32];
    __shared__ unsigned short Bs[128 * 32];

    const int tid  = threadIdx.x;
    const int wave = tid >> 6;
    const int lane = tid & 63;
    const int quad = lane >> 4;
    const int l16  = lane & 15;
    const int bm   = blockIdx.x * 128;
    const int bn   = blockIdx.y * 128;
    const int wm   = (wave >> 1) * 64;
    const int wn   = (wave & 1) * 64;

    f32x4 acc[4][4] = {};

    for (int k0 = 0; k0 < D_IN; k0 += 32) {
        __syncthreads();   // previous iteration's LDS reads complete
        // stage A-tile and B-tile: 512 chunks of 16B each, 2 per thread per tile
#pragma unroll
        for (int c = 0; c < 2; ++c) {
            const int wbase = c * 256 + wave * 64;       // wave-uniform chunk base
            const int idx   = wbase + lane;
            const int row   = idx >> 2;
            const int cc    = idx & 3;
            async16(A + (size_t)(bm + row) * D_IN + k0 + cc * 8, As + (size_t)wbase * 8);
            async16(W + (size_t)(bn + row) * D_IN + k0 + cc * 8, Bs + (size_t)wbase * 8);
        }
        __syncthreads();   // compiler inserts vmcnt(0) drain before barrier

        bf16x8 af[4], bf[4];
#pragma unroll
        for (int t = 0; t < 4; ++t) {
            af[t] = *(const bf16x8*)&As[(wm + t * 16 + l16) * 32 + quad * 8];
            bf[t] = *(const bf16x8*)&Bs[(wn + t * 16 + l16) * 32 + quad * 8];
        }
#pragma unroll
        for (int i = 0; i < 4; ++i)
#pragma unroll
            for (int j = 0; j < 4; ++j)
                acc[i][j] = __builtin_amdgcn_mfma_f32_16x16x32_bf16(af[i], bf[j], acc[i][j], 0, 0, 0);
    }

    // C/D layout (16x16): col = lane&15 (n), row = quad*4 + r (m)
    if (bn < D_OUT) {
#pragma unroll
        for (int j = 0; j < 4; ++j) {
            const int n = bn + wn + j * 16 + l16;
            const float bias = b1[n];
#pragma unroll
            for (int i = 0; i < 4; ++i) {
#pragma unroll
                for (int r = 0; r < 4; ++r) {
                    const int m = bm + wm + i * 16 + quad * 4 + r;
                    out[(size_t)m * D_OUT + n] = acc[i][j][r] + bias;
                }
            }
        }
    } else {
#pragma unroll
        for (int j = 0; j < 4; ++j) {
            const int n = bn - D_OUT + wn + j * 16 + l16;
#pragma unroll
            for (int i = 0; i < 4; ++i) {
#pragma unroll
                for (int r = 0; r < 4; ++r) {
                    const int m = bm + wm + i * 16 + quad * 4 + r;
                    Y2[(size_t)m * D_OUT + n] = acc[i][j][r];
                }
            }
        }
    }
}

// per-class sum of Y2 rows + fused grand-total via atomics
__global__ void classsum_kernel(const float* __restrict__ Y2,
                                const int* __restrict__ offs,
                                const int* __restrict__ cnt,
                                const int* __restrict__ rowlist,
                                float* __restrict__ t_out,
                                float* __restrict__ T2) {
    int c = blockIdx.x;
    int j = threadIdx.x;
    int o = offs[c], n = cnt[c];
    float acc = 0.f;
    for (int r = 0; r < n; ++r) {
        int row = rowlist[o + r];
        acc += Y2[(size_t)row * D_OUT + j];
    }
    t_out[(size_t)c * D_OUT + j] = acc;
    atomicAdd(&T2[j], acc);
}

__global__ void z_kernel(const float* __restrict__ t_in,
                         const float* __restrict__ T2,
                         const float* __restrict__ b2,
                         const int* __restrict__ cnt,
                         float* __restrict__ Z) {
    int c = blockIdx.x;
    int j = threadIdx.x;
    int d = B - cnt[c];
    float v = b2[j];
    if (d > 0) v += (T2[j] - t_in[(size_t)c * D_OUT + j]) / (float)d;
    Z[(size_t)c * D_OUT + j] = v;
}

__global__ void final_kernel(float* __restrict__ out,
                             const float* __restrict__ Z,
                             const int* __restrict__ label) {
    int idx = blockIdx.x * blockDim.x + threadIdx.x;  // float4 index
    int i  = idx >> 6;
    int j4 = (idx & 63) << 2;
    int c = label[i];
    float4 o = *(float4*)(out + (size_t)idx * 4);
    float4 z = *(const float4*)(Z + (size_t)c * D_OUT + j4);
    o.x += z.x; o.y += z.y; o.z += z.z; o.w += z.w;
    *(float4*)(out + (size_t)idx * 4) = o;
}

// ---------------- launcher ----------------
extern "C" void kernel_launch(void* const* d_in, const int* in_sizes, int n_in,
                              void* d_out, int out_size, void* d_ws, size_t ws_size,
                              hipStream_t stream) {
    const float* x    = (const float*)d_in[0];
    const int*   lab  = (const int*)d_in[1];
    const float* W1_w = (const float*)d_in[2];
    const float* W1_b = (const float*)d_in[3];
    const float* W2_w = (const float*)d_in[4];
    const float* W2_b = (const float*)d_in[5];
    float* out = (float*)d_out;

    char* ws = (char*)d_ws;
    unsigned short* xb = (unsigned short*)(ws + OFF_XB);
    unsigned short* Wb = (unsigned short*)(ws + OFF_WB);
    float* Y2  = (float*)(ws + OFF_Y2);
    float* t_c = (float*)(ws + OFF_T);
    float* Z   = (float*)(ws + OFF_Z);
    float* T2  = (float*)(ws + OFF_T2);
    int*   ints = (int*)(ws + OFF_INT);
    int* cnt     = ints;
    int* offs    = ints + NCLS;
    int* cursor  = ints + 2 * NCLS;
    int* rowlist = ints + 3 * NCLS;

    // 1. zero T2 (256 f32 == 256 ints of 0) + cnt/offs/cursor, contiguous region
    zero_ints_kernel<<<(D_OUT + 3 * NCLS + 255) / 256, 256, 0, stream>>>((int*)T2, D_OUT + 3 * NCLS);
    // 2. histogram
    hist_kernel<<<B / 256, 256, 0, stream>>>(lab, cnt);
    // 3. exclusive prefix
    prefix_kernel<<<1, 1024, 0, stream>>>(cnt, offs);
    // 4. scatter row indices (counting sort)
    scatter_kernel<<<B / 256, 256, 0, stream>>>(lab, offs, cursor, rowlist);
    // 5. bf16 conversions
    cvt_x_kernel<<<(B * D_IN / 8) / 256, 256, 0, stream>>>(x, xb);
    cvt_w_kernel<<<(NCAT * D_IN / 8) / 256, 256, 0, stream>>>(W1_w, W2_w, Wb);
    // 6. MFMA GEMM: out (with b1) + Y2
    dim3 ggrid(B / 128, NCAT / 128);
    gemm_mfma_kernel<<<ggrid, 256, 0, stream>>>(xb, Wb, W1_b, out, Y2);
    // 7. per-class sums + grand total
    classsum_kernel<<<NCLS, D_OUT, 0, stream>>>(Y2, offs, cnt, rowlist, t_c, T2);
    // 8. Z table
    z_kernel<<<NCLS, D_OUT, 0, stream>>>(t_c, T2, W2_b, cnt, Z);
    // 9. gather-add
    final_kernel<<<(B * D_OUT / 4) / 256, 256, 0, stream>>>(out, Z, lab);
}